// Round 4
// baseline (497.249 us; speedup 1.0000x reference)
//
#include <hip/hip_runtime.h>

typedef unsigned short ushort_t;
typedef unsigned int uint_t;
typedef __attribute__((ext_vector_type(8))) short bhalf8;    // 8 bf16 (4 VGPRs)
typedef __attribute__((ext_vector_type(16))) float f32x16;   // 32x32 MFMA acc

#define C_LIN  0.04419417382415922f     // 1/sqrt(512)
#define C_CONV 0.014731391274719738f    // 1/sqrt(512*9)

__device__ __forceinline__ ushort_t f2bf(float f) {
    uint_t u = __float_as_uint(f);
    u += 0x7fffu + ((u >> 16) & 1u);    // round-to-nearest-even
    return (ushort_t)(u >> 16);
}

__device__ __forceinline__ void gload16(const void* g, void* l) {
    __builtin_amdgcn_global_load_lds((const __attribute__((address_space(1))) void*)g,
                                     (__attribute__((address_space(3))) void*)l, 16, 0, 0);
}

// ---------------- mapping-network layer: zout = act(zin @ (w*C_LIN)^T + b) --
__global__ void map_layer_k(const float* __restrict__ zin, const float* __restrict__ w,
                            const float* __restrict__ bias, const float* __restrict__ alpha,
                            float* __restrict__ zout, int final_) {
    __shared__ float zs[512];
    const int b = blockIdx.y, tid = threadIdx.x;
    if (tid < 128) ((float4*)zs)[tid] = ((const float4*)(zin + b * 512))[tid];
    __syncthreads();
    const int j = blockIdx.x * 64 + (tid >> 2);
    const int part = (tid & 3) * 128;
    const float4* wr = (const float4*)(w + (size_t)j * 512 + part);
    const float* zp = zs + part;
    float acc = 0.f;
#pragma unroll 8
    for (int i = 0; i < 32; ++i) {
        float4 w4 = wr[i];
        acc += w4.x * zp[4*i] + w4.y * zp[4*i+1] + w4.z * zp[4*i+2] + w4.w * zp[4*i+3];
    }
    acc += __shfl_xor(acc, 1);
    acc += __shfl_xor(acc, 2);
    if ((tid & 3) == 0) {
        acc = acc * C_LIN + bias[j];
        if (final_) acc *= C_CONV;                       // fold c_conv into style
        else        acc = acc >= 0.f ? acc : alpha[j] * acc;
        zout[b * 512 + j] = acc;
    }
}

// ---------------- fused: wsq[co][ci] = sum_tap cw^2 ; wbf[tap][co][ci] = bf16(cw)
__global__ void wsqbf_k(const float* __restrict__ cw, float* __restrict__ wsq,
                        ushort_t* __restrict__ wbf) {
    int idx = blockIdx.x * 256 + threadIdx.x;   // (co*512+ci) < 262144
    const float* p = cw + (size_t)idx * 9;
    float v[9], sum = 0.f;
#pragma unroll
    for (int k = 0; k < 9; ++k) { v[k] = p[k]; sum += v[k] * v[k]; }
    wsq[idx] = sum;
#pragma unroll
    for (int k = 0; k < 9; ++k)
        wbf[(size_t)k * 262144 + idx] = f2bf(v[k]);
}

// ---------------- sigma_inv[b][cout] ----------------------------------------
__global__ void sigma_k(const float* __restrict__ style_c, const float* __restrict__ wsq,
                        float* __restrict__ sig) {
    __shared__ float s2[512];
    const int b = blockIdx.x, c = threadIdx.x;
    float v = style_c[b * 512 + c];
    s2[c] = v * v;
    __syncthreads();
    const float4* wr = (const float4*)(wsq + (size_t)c * 512);
    float acc = 0.f;
    for (int i = 0; i < 128; ++i) {
        float4 w = wr[i];
        acc += w.x * s2[4*i] + w.y * s2[4*i+1] + w.z * s2[4*i+2] + w.w * s2[4*i+3];
    }
    sig[b * 512 + c] = 1.0f / sqrtf(acc + 1e-8f);
}

// ---------------- x -> bf16 NHWC, style-modulated ---------------------------
__global__ void xmod_k(const float* __restrict__ x, const float* __restrict__ style_c,
                       ushort_t* __restrict__ xm) {
    const int y = blockIdx.x, b = blockIdx.y, tid = threadIdx.x;
    const float* xp = x + ((size_t)b * 512) * 4096 + y * 64;            // x[b][ci][y][0]
    ushort_t* op = xm + (((size_t)b * 64 + y) * 64) * 512;              // xm[b][y][x][ci]
    __shared__ ushort_t tile[32][65];
    for (int cin0 = 0; cin0 < 512; cin0 += 32) {
        for (int i = tid; i < 2048; i += 256) {                         // (ci, x) load, coalesced
            int ci = i >> 6, xc = i & 63;
            float v = xp[(size_t)(cin0 + ci) * 4096 + xc] * style_c[b * 512 + cin0 + ci];
            tile[ci][xc] = f2bf(v);
        }
        __syncthreads();
        for (int i = tid; i < 2048; i += 256) {                         // (x, ci) store, ci fastest
            int xc = i >> 5, ci = i & 31;
            op[(size_t)xc * 512 + cin0 + ci] = tile[ci][xc];
        }
        __syncthreads();
    }
}

// ---------------- implicit-GEMM conv via 32x32x16 MFMA ----------------------
// Block: 64 couts x (8 rows x 64 cols). 4 waves, each 64 couts x 2 rows.
// LDS layout identical to round 3 (16B-block sigma-swizzle in 32-block windows:
// physical (k=bits[4:3], s=bits[2:0]) holds logical (pos = s^2k, group k)).
// Only the read addressing / MFMA shape / epilogue changed.
template <bool XPRE>
__global__ __launch_bounds__(256, 2)
void conv_k(const float* __restrict__ x, const ushort_t* __restrict__ xm,
            const ushort_t* __restrict__ wbf, const float* __restrict__ style_c,
            const float* __restrict__ sig, float* __restrict__ out) {
    __shared__ __align__(16) ushort_t wt[18432];   // 36864 B: 9 taps x 64 co x 32 ci
    __shared__ __align__(16) ushort_t xs[21504];   // 43008 B: 2688 16B-blocks

    const int tid  = threadIdx.x;
    const int lane = tid & 63;
    const int wv   = tid >> 6;
    const int l31  = lane & 31, lhi = lane >> 5;

    // XCD-aware bijective block swizzle (nwg=1024, 8 XCDs): batch-major chunks.
    const int bid = blockIdx.x;
    const int swz = (bid & 7) * 128 + (bid >> 3);
    const int b     = swz >> 6;
    const int cout0 = ((swz >> 3) & 7) * 64;
    const int r0    = (swz & 7) * 8;

    const int nx = (wv < 2) ? 11 : 10;             // X slots per wave (42 total)

    // ---- per-thread staging source offsets (element units, +c0 per chunk)
    int gw[9];
#pragma unroll
    for (int t = 0; t < 9; ++t) {
        int L = (wv * 9 + t) * 64 + lane;          // physical 16B-block in wt
        int tap = L >> 8, win = (L >> 5) & 7, k = (L >> 3) & 3, s = L & 7;
        int c = win * 8 + ((s ^ (k * 2)) & 7);     // logical cout_local
        gw[t] = ((tap * 512 + cout0 + c) << 9) + k * 8;
    }
    int gxo[11];
#pragma unroll
    for (int t = 0; t < 11; ++t) {
        if (t < nx) {
            int L = (wv + 4 * t) * 64 + lane;      // physical block in xs, slot u=wv+4t
            int k = (L >> 3) & 3, s = L & 7;
            int p = ((L >> 5) << 3) | ((s ^ (k * 2)) & 7);
            p = min(p, 659);                        // pad-region lanes: safe duplicate
            int row = p / 66, col = p - row * 66;
            int gy = min(max(r0 - 1 + row, 0), 63);
            int gx = min(max(col - 1, 0), 63);
            gxo[t] = (((b * 64 + gy) * 64 + gx) << 9) + k * 8;   // xm element offset
        } else gxo[t] = 0;
    }

    f32x16 acc[2][2][2] = {};                      // [r_out][m][n]
    // A-frag per-lane addressing: co = m*32+l31, g = kstep*2+lhi
    const int A0 = (l31 >> 3) * 32;
    int afk[2];
#pragma unroll
    for (int k = 0; k < 2; ++k) {
        int g = k * 2 + lhi;
        afk[k] = g * 8 + ((l31 & 7) ^ ((2 * g) & 7));
    }

    for (int c0 = 0; c0 < 512; c0 += 32) {
        __syncthreads();                            // prev chunk's readers done
        // ---- stage W (linear LDS dest, pre-swizzled global source)
#pragma unroll
        for (int t = 0; t < 9; ++t)
            gload16(wbf + gw[t] + c0, (char*)wt + (wv * 9 + t) * 1024);
        // ---- stage X
        if (XPRE) {
#pragma unroll
            for (int t = 0; t < 11; ++t)
                if (t < nx)
                    gload16(xm + gxo[t] + c0, (char*)xs + (wv + 4 * t) * 1024);
        } else {
#pragma unroll
            for (int t = 0; t < 11; ++t) {
                if (t < nx) {
                    int L = (wv + 4 * t) * 64 + lane;
                    int k = (L >> 3) & 3, s = L & 7;
                    int p = ((L >> 5) << 3) | ((s ^ (k * 2)) & 7);
                    p = min(p, 659);
                    int row = p / 66, col = p - row * 66;
                    int gy = min(max(r0 - 1 + row, 0), 63);
                    int gx = min(max(col - 1, 0), 63);
                    const float* xp = x + ((size_t)(b * 512 + c0 + k * 8)) * 4096 + gy * 64 + gx;
                    const float* sc = style_c + b * 512 + c0 + k * 8;
                    ushort_t tmp[8];
#pragma unroll
                    for (int e = 0; e < 8; ++e)
                        tmp[e] = f2bf(xp[(size_t)e * 4096] * sc[e]);
                    *(bhalf8*)((char*)xs + (size_t)L * 16) = *(const bhalf8*)tmp;
                }
            }
        }
        asm volatile("s_waitcnt vmcnt(0)" ::: "memory");
        __syncthreads();

        // ---- compute: dx-major, af held for all dy, bfr per input row
#pragma unroll
        for (int dx = 0; dx < 3; ++dx) {
            bhalf8 af[3][2][2];                     // [dy][m][kstep]
#pragma unroll
            for (int dy = 0; dy < 3; ++dy)
#pragma unroll
                for (int m = 0; m < 2; ++m)
#pragma unroll
                    for (int k = 0; k < 2; ++k)
                        af[dy][m][k] = *(const bhalf8*)((const char*)wt +
                            (((dy * 3 + dx) * 256 + m * 128 + A0 + afk[k]) << 4));
#pragma unroll
            for (int ri = 0; ri < 4; ++ri) {
                const int p0 = (wv * 2 + ri) * 66 + dx + l31;
                bhalf8 bfr[2][2];                   // [n][kstep]
#pragma unroll
                for (int n = 0; n < 2; ++n)
#pragma unroll
                    for (int k = 0; k < 2; ++k) {
                        int p = p0 + n * 32;
                        int g = k * 2 + lhi;
                        int blk = ((p >> 3) << 5) + g * 8 + ((p & 7) ^ ((2 * g) & 7));
                        bfr[n][k] = *(const bhalf8*)((const char*)xs + (blk << 4));
                    }
#pragma unroll
                for (int dy = 0; dy < 3; ++dy) {
                    const int r_out = ri - dy;
                    if (r_out < 0 || r_out > 1) continue;
#pragma unroll
                    for (int k = 0; k < 2; ++k)
#pragma unroll
                        for (int m = 0; m < 2; ++m)
#pragma unroll
                            for (int n = 0; n < 2; ++n)
                                acc[r_out][m][n] = __builtin_amdgcn_mfma_f32_32x32x16_bf16(
                                    af[dy][m][k], bfr[n][k], acc[r_out][m][n], 0, 0, 0);
                }
            }
        }
    }

    // ---- epilogue: demodulate + store
    // C/D (32x32): col = lane&31, row = (reg&3) + 8*(reg>>2) + 4*(lane>>5)
#pragma unroll
    for (int m = 0; m < 2; ++m) {
#pragma unroll
        for (int reg = 0; reg < 16; ++reg) {
            const int co = m * 32 + (reg & 3) + 8 * (reg >> 2) + 4 * lhi;
            const int cout = cout0 + co;
            const float sg = sig[b * 512 + cout];
            float* opc = out + (((size_t)b * 512 + cout) * 64 + r0 + wv * 2) * 64;
#pragma unroll
            for (int r_out = 0; r_out < 2; ++r_out)
#pragma unroll
                for (int n = 0; n < 2; ++n)
                    opc[r_out * 64 + n * 32 + l31] = acc[r_out][m][n][reg] * sg;
        }
    }
}

// ---------------- launch ----------------------------------------------------
extern "C" void kernel_launch(void* const* d_in, const int* in_sizes, int n_in,
                              void* d_out, int out_size, void* d_ws, size_t ws_size,
                              hipStream_t stream) {
    const float* x  = (const float*)d_in[0];
    const float* s  = (const float*)d_in[1];
    const float* w0 = (const float*)d_in[2];
    const float* b0 = (const float*)d_in[3];
    const float* a0 = (const float*)d_in[4];
    const float* w1 = (const float*)d_in[5];
    const float* b1 = (const float*)d_in[6];
    const float* a1 = (const float*)d_in[7];
    const float* sw = (const float*)d_in[8];
    const float* sb = (const float*)d_in[9];
    const float* cw = (const float*)d_in[10];
    float* out = (float*)d_out;

    // workspace layout (f32 elements unless noted)
    float*    style_c = (float*)d_ws;                       // 8192
    float*    sig     = style_c + 8192;                     // 8192
    float*    zt0     = sig + 8192;                         // 8192
    float*    zt1     = zt0 + 8192;                         // 8192
    float*    wsq     = zt1 + 8192;                         // 262144
    ushort_t* wbf     = (ushort_t*)(wsq + 262144);          // 2359296 bf16
    ushort_t* xm      = (ushort_t*)((char*)d_ws + 5898240); // 33554432 bf16 (67.1 MB)
    const bool xpre = ws_size >= 73007104ull;

    wsqbf_k<<<1024, 256, 0, stream>>>(cw, wsq, wbf);
    map_layer_k<<<dim3(8, 16), 256, 0, stream>>>(s,   w0, b0, a0, zt0,     0);
    map_layer_k<<<dim3(8, 16), 256, 0, stream>>>(zt0, w1, b1, a1, zt1,     0);
    map_layer_k<<<dim3(8, 16), 256, 0, stream>>>(zt1, sw, sb, a1, style_c, 1);
    sigma_k<<<16, 512, 0, stream>>>(style_c, wsq, sig);
    if (xpre) {
        xmod_k<<<dim3(64, 16), 256, 0, stream>>>(x, style_c, xm);
        conv_k<true><<<1024, 256, 0, stream>>>(x, xm, wbf, style_c, sig, out);
    } else {
        conv_k<false><<<1024, 256, 0, stream>>>(x, xm, wbf, style_c, sig, out);
    }
}

// Round 5
// 323.636 us; speedup vs baseline: 1.5364x; 1.5364x over previous
//
#include <hip/hip_runtime.h>

typedef unsigned short ushort_t;
typedef unsigned int uint_t;
typedef __attribute__((ext_vector_type(8))) short bhalf8;   // 8 bf16 (4 VGPRs)
typedef __attribute__((ext_vector_type(4))) float f32x4;

#define C_LIN  0.04419417382415922f     // 1/sqrt(512)
#define C_CONV 0.014731391274719738f    // 1/sqrt(512*9)

__device__ __forceinline__ ushort_t f2bf(float f) {
    uint_t u = __float_as_uint(f);
    u += 0x7fffu + ((u >> 16) & 1u);    // round-to-nearest-even
    return (ushort_t)(u >> 16);
}

__device__ __forceinline__ void gload16(const void* g, void* l) {
    __builtin_amdgcn_global_load_lds((const __attribute__((address_space(1))) void*)g,
                                     (__attribute__((address_space(3))) void*)l, 16, 0, 0);
}

// ---------------- mapping-network layer: zout = act(zin @ (w*C_LIN)^T + b) --
__global__ void map_layer_k(const float* __restrict__ zin, const float* __restrict__ w,
                            const float* __restrict__ bias, const float* __restrict__ alpha,
                            float* __restrict__ zout, int final_) {
    __shared__ float zs[512];
    const int b = blockIdx.y, tid = threadIdx.x;
    if (tid < 128) ((float4*)zs)[tid] = ((const float4*)(zin + b * 512))[tid];
    __syncthreads();
    const int j = blockIdx.x * 64 + (tid >> 2);
    const int part = (tid & 3) * 128;
    const float4* wr = (const float4*)(w + (size_t)j * 512 + part);
    const float* zp = zs + part;
    float acc = 0.f;
#pragma unroll 8
    for (int i = 0; i < 32; ++i) {
        float4 w4 = wr[i];
        acc += w4.x * zp[4*i] + w4.y * zp[4*i+1] + w4.z * zp[4*i+2] + w4.w * zp[4*i+3];
    }
    acc += __shfl_xor(acc, 1);
    acc += __shfl_xor(acc, 2);
    if ((tid & 3) == 0) {
        acc = acc * C_LIN + bias[j];
        if (final_) acc *= C_CONV;                       // fold c_conv into style
        else        acc = acc >= 0.f ? acc : alpha[j] * acc;
        zout[b * 512 + j] = acc;
    }
}

// ---- fused prep: wsq[co][ci] = sum_tap cw^2 ; wbf2 = bf16(cw) in frag order -
// wbf2 elem addr for (tap, cout, ci):
//   block = ((tap*8 + cout>>6)*16 + ci>>5)*4 + (cout>>4)&3   (512 elems each)
//   in-block = (((ci>>3)&3)*16 + cout&15)*8 + ci&7           (= lane*8 + e)
__global__ void wsqbf_k(const float* __restrict__ cw, float* __restrict__ wsq,
                        ushort_t* __restrict__ wbf2) {
    int idx = blockIdx.x * 256 + threadIdx.x;   // cout*512 + ci, < 262144
    int cout = idx >> 9, ci = idx & 511;
    const float* p = cw + (size_t)idx * 9;
    float v[9], sum = 0.f;
#pragma unroll
    for (int k = 0; k < 9; ++k) { v[k] = p[k]; sum += v[k] * v[k]; }
    wsq[idx] = sum;
    const size_t base = ((size_t)(((cout >> 6) * 16 + (ci >> 5)) * 4 + ((cout >> 4) & 3))) * 512
                        + (((ci >> 3) & 3) * 16 + (cout & 15)) * 8 + (ci & 7);
#pragma unroll
    for (int k = 0; k < 9; ++k)
        wbf2[(size_t)k * 262144 + base] = f2bf(v[k]);   // tap stride = 8*16*4*512
}

// ---------------- sigma_inv[b][cout], 256 blocks ----------------------------
__global__ void sigma_k(const float* __restrict__ style_c, const float* __restrict__ wsq,
                        float* __restrict__ sig) {
    __shared__ float s2[512];
    const int b = blockIdx.y, cb = blockIdx.x, tid = threadIdx.x;
    if (tid < 128) {
        float4 sv = ((const float4*)(style_c + b * 512))[tid];
        s2[4*tid]   = sv.x * sv.x; s2[4*tid+1] = sv.y * sv.y;
        s2[4*tid+2] = sv.z * sv.z; s2[4*tid+3] = sv.w * sv.w;
    }
    __syncthreads();
    const int c = cb * 32 + (tid >> 3);
    const int part = (tid & 7) * 64;
    const float4* wr = (const float4*)(wsq + (size_t)c * 512 + part);
    const float* zp = s2 + part;
    float acc = 0.f;
#pragma unroll
    for (int i = 0; i < 16; ++i) {
        float4 w = wr[i];
        acc += w.x * zp[4*i] + w.y * zp[4*i+1] + w.z * zp[4*i+2] + w.w * zp[4*i+3];
    }
    acc += __shfl_xor(acc, 1);
    acc += __shfl_xor(acc, 2);
    acc += __shfl_xor(acc, 4);
    if ((tid & 7) == 0) sig[b * 512 + c] = 1.0f / sqrtf(acc + 1e-8f);
}

// ---------------- x -> bf16 NHWC, style-modulated ---------------------------
__global__ void xmod_k(const float* __restrict__ x, const float* __restrict__ style_c,
                       ushort_t* __restrict__ xm) {
    const int y = blockIdx.x, b = blockIdx.y, tid = threadIdx.x;
    const float* xp = x + ((size_t)b * 512) * 4096 + y * 64;            // x[b][ci][y][0]
    ushort_t* op = xm + (((size_t)b * 64 + y) * 64) * 512;              // xm[b][y][x][ci]
    __shared__ ushort_t tile[32][68];
    for (int cin0 = 0; cin0 < 512; cin0 += 32) {
#pragma unroll
        for (int t = 0; t < 2; ++t) {                                   // float4 loads
            int i = tid + t * 256;                                      // < 512
            int ci = i >> 4, x4 = i & 15;
            float4 v = *(const float4*)(xp + (size_t)(cin0 + ci) * 4096 + x4 * 4);
            float sc = style_c[b * 512 + cin0 + ci];
            tile[ci][x4*4]   = f2bf(v.x * sc); tile[ci][x4*4+1] = f2bf(v.y * sc);
            tile[ci][x4*4+2] = f2bf(v.z * sc); tile[ci][x4*4+3] = f2bf(v.w * sc);
        }
        __syncthreads();
#pragma unroll
        for (int t = 0; t < 4; ++t) {                                   // ushort2 stores
            int i = tid + t * 256;                                      // < 1024
            int xc = i >> 4, c2 = i & 15;
            ushort2 pr;
            pr.x = tile[c2*2][xc]; pr.y = tile[c2*2+1][xc];
            *(ushort2*)(op + (size_t)xc * 512 + cin0 + c2 * 2) = pr;
        }
        __syncthreads();
    }
}

// ---------------- implicit-GEMM conv via 16x16x32 MFMA ----------------------
// Block: 64 couts x (8 rows x 64 cols). 4 waves, each 64 couts x 2 rows.
// X tile in LDS with 16B-block sigma-swizzle in 32-block windows:
//   physical (k=bits[4:3], s=bits[2:0]) holds logical (pos = s^2k, group k).
// W (A-frags) read directly from global wbf2 (fragment-ordered, L2-resident).
template <bool XPRE>
__global__ __launch_bounds__(256, 2)
void conv_k(const float* __restrict__ x, const ushort_t* __restrict__ xm,
            const ushort_t* __restrict__ wbf2, const float* __restrict__ style_c,
            const float* __restrict__ sig, float* __restrict__ out) {
    __shared__ __align__(16) ushort_t xs[21504];   // 43008 B: 2688 16B-blocks

    const int tid  = threadIdx.x;
    const int lane = tid & 63;
    const int wv   = tid >> 6;
    const int l15  = lane & 15, l4 = lane >> 4;

    // XCD-aware bijective block swizzle (nwg=1024, 8 XCDs): batch-major chunks.
    const int bid = blockIdx.x;
    const int swz = (bid & 7) * 128 + (bid >> 3);
    const int b     = swz >> 6;
    const int cout0 = ((swz >> 3) & 7) * 64;
    const int r0    = (swz & 7) * 8;

    const int nx = (wv < 2) ? 11 : 10;             // X slots per wave (42 total)

    // ---- X staging source offsets (element units, +c0 per chunk)
    int gxo[11];
#pragma unroll
    for (int t = 0; t < 11; ++t) {
        if (t < nx) {
            int L = (wv + 4 * t) * 64 + lane;      // physical block in xs, slot u=wv+4t
            int k = (L >> 3) & 3, s = L & 7;
            int p = ((L >> 5) << 3) | ((s ^ (k * 2)) & 7);
            p = min(p, 659);                        // pad-region lanes: safe duplicate
            int row = p / 66, col = p - row * 66;
            int gy = min(max(r0 - 1 + row, 0), 63);
            int gx = min(max(col - 1, 0), 63);
            gxo[t] = (((b * 64 + gy) * 64 + gx) << 9) + k * 8;   // xm element offset
        } else gxo[t] = 0;
    }

    // A-frag global base: per (tap, m) a wave reads 1024 contiguous bytes.
    // elem = (((tap*8 + co6)*16 + kc)*4 + m)*512 + lane*8
    const ushort_t* wbase = wbf2 + (size_t)(cout0 >> 6) * 16 * 4 * 512 + lane * 8;

    f32x4 acc[2][4][4] = {};

    for (int c0 = 0; c0 < 512; c0 += 32) {
        __syncthreads();                            // prev chunk's readers done
        // ---- stage X (linear LDS dest, pre-swizzled global source)
        if (XPRE) {
#pragma unroll
            for (int t = 0; t < 11; ++t)
                if (t < nx)
                    gload16(xm + gxo[t] + c0, (char*)xs + (wv + 4 * t) * 1024);
        } else {
#pragma unroll
            for (int t = 0; t < 11; ++t) {
                if (t < nx) {
                    int L = (wv + 4 * t) * 64 + lane;
                    int k = (L >> 3) & 3, s = L & 7;
                    int p = ((L >> 5) << 3) | ((s ^ (k * 2)) & 7);
                    p = min(p, 659);
                    int row = p / 66, col = p - row * 66;
                    int gy = min(max(r0 - 1 + row, 0), 63);
                    int gx = min(max(col - 1, 0), 63);
                    const float* xp = x + ((size_t)(b * 512 + c0 + k * 8)) * 4096 + gy * 64 + gx;
                    const float* sc = style_c + b * 512 + c0 + k * 8;
                    ushort_t tmp[8];
#pragma unroll
                    for (int e = 0; e < 8; ++e)
                        tmp[e] = f2bf(xp[(size_t)e * 4096] * sc[e]);
                    *(bhalf8*)((char*)xs + (size_t)L * 16) = *(const bhalf8*)tmp;
                }
            }
        }
        asm volatile("s_waitcnt vmcnt(0)" ::: "memory");
        __syncthreads();

        const ushort_t* wk = wbase + (size_t)(c0 >> 5) * 4 * 512;

        // ---- compute: dx-major; af from GLOBAL (L2-resident), bfr from LDS
#pragma unroll
        for (int dx = 0; dx < 3; ++dx) {
            bhalf8 af[3][4];
#pragma unroll
            for (int dy = 0; dy < 3; ++dy)
#pragma unroll
                for (int m = 0; m < 4; ++m)
                    af[dy][m] = *(const bhalf8*)(wk + ((size_t)(dy * 3 + dx) * 8 * 16 * 4 + m) * 512);
#pragma unroll
            for (int ri = 0; ri < 4; ++ri) {
                const int p0 = (wv * 2 + ri) * 66 + dx + l15;
                const int bb = (p0 >> 3) * 512 + l4 * 128 + (((p0 & 7) ^ (l4 * 2)) & 7) * 16;
                bhalf8 bfr[4];
#pragma unroll
                for (int n = 0; n < 4; ++n)
                    bfr[n] = *(const bhalf8*)((const char*)xs + bb + n * 1024);
#pragma unroll
                for (int dy = 0; dy < 3; ++dy) {
                    const int r_out = ri - dy;
                    if (r_out < 0 || r_out > 1) continue;
#pragma unroll
                    for (int m = 0; m < 4; ++m)
#pragma unroll
                        for (int n = 0; n < 4; ++n)
                            acc[r_out][m][n] = __builtin_amdgcn_mfma_f32_16x16x32_bf16(
                                af[dy][m], bfr[n], acc[r_out][m][n], 0, 0, 0);
                }
            }
        }
    }

    // ---- epilogue: demodulate + store (C/D: col=lane&15, row=(lane>>4)*4+reg)
#pragma unroll
    for (int r_out = 0; r_out < 2; ++r_out) {
        const int orow = r0 + wv * 2 + r_out;
#pragma unroll
        for (int m = 0; m < 4; ++m) {
#pragma unroll
            for (int r = 0; r < 4; ++r) {
                int cout = cout0 + m * 16 + l4 * 4 + r;
                float sg = sig[b * 512 + cout];
                float* op = out + (((size_t)b * 512 + cout) * 64 + orow) * 64;
#pragma unroll
                for (int n = 0; n < 4; ++n)
                    op[n * 16 + l15] = acc[r_out][m][n][r] * sg;
            }
        }
    }
}

// ---------------- launch ----------------------------------------------------
extern "C" void kernel_launch(void* const* d_in, const int* in_sizes, int n_in,
                              void* d_out, int out_size, void* d_ws, size_t ws_size,
                              hipStream_t stream) {
    const float* x  = (const float*)d_in[0];
    const float* s  = (const float*)d_in[1];
    const float* w0 = (const float*)d_in[2];
    const float* b0 = (const float*)d_in[3];
    const float* a0 = (const float*)d_in[4];
    const float* w1 = (const float*)d_in[5];
    const float* b1 = (const float*)d_in[6];
    const float* a1 = (const float*)d_in[7];
    const float* sw = (const float*)d_in[8];
    const float* sb = (const float*)d_in[9];
    const float* cw = (const float*)d_in[10];
    float* out = (float*)d_out;

    // workspace layout (f32 elements unless noted)
    float*    style_c = (float*)d_ws;                       // 8192
    float*    sig     = style_c + 8192;                     // 8192
    float*    zt0     = sig + 8192;                         // 8192
    float*    zt1     = zt0 + 8192;                         // 8192
    float*    wsq     = zt1 + 8192;                         // 262144
    ushort_t* wbf2    = (ushort_t*)(wsq + 262144);          // 2359296 bf16
    ushort_t* xm      = (ushort_t*)((char*)d_ws + 5898240); // 33554432 bf16 (67.1 MB)
    const bool xpre = ws_size >= 73007104ull;

    wsqbf_k<<<1024, 256, 0, stream>>>(cw, wsq, wbf2);
    map_layer_k<<<dim3(8, 16), 256, 0, stream>>>(s,   w0, b0, a0, zt0,     0);
    map_layer_k<<<dim3(8, 16), 256, 0, stream>>>(zt0, w1, b1, a1, zt1,     0);
    map_layer_k<<<dim3(8, 16), 256, 0, stream>>>(zt1, sw, sb, a1, style_c, 1);
    sigma_k<<<dim3(16, 16), 256, 0, stream>>>(style_c, wsq, sig);
    if (xpre) {
        xmod_k<<<dim3(64, 16), 256, 0, stream>>>(x, style_c, xm);
        conv_k<true><<<1024, 256, 0, stream>>>(x, xm, wbf2, style_c, sig, out);
    } else {
        conv_k<false><<<1024, 256, 0, stream>>>(x, xm, wbf2, style_c, sig, out);
    }
}